// Round 3
// baseline (217.345 us; speedup 1.0000x reference)
//
#include <hip/hip_runtime.h>
#include <hip/hip_bf16.h>

// 15x15 VALID conv (cross-correlation) of 4096x4096 f32 -> 4082x4082 f32, + bias.
//
// Block: 256 threads = 4 waves. Output tile 256(x) x 32(y).
// Thread: tx = tid&63 (x), ty = tid>>6 (wave id, y). Computes 4 cols x 8 rows.
// LDS input tile: 46 rows x 272 floats (270 used) = 49 KB -> 3 blocks/CU.
// ky is chunked 5 x 3 so per-chunk weights (45) stay in registers/SGPRs and
// every LDS input row is read once per chunk (sliding-window kx reuse in regs).

#define IN_DIM   4096
#define OUT_DIM  4082   // 4096 - 15 + 1
#define KDIM     15
#define BTX      256    // block output tile x
#define BTY      32     // block output tile y
#define TIN_Y    46     // BTY + 14
#define TIN_XP   272    // BTX + 14 = 270, padded to 272 (16B multiple)
#define KCH      3      // ky rows per chunk
#define NCH      5      // number of chunks

__global__ __launch_bounds__(256) void conv15_kernel(
    const float* __restrict__ X, const float* __restrict__ Wt,
    const float* __restrict__ bias, float* __restrict__ out) {
  __shared__ float sX[TIN_Y * TIN_XP];

  const int tid = threadIdx.x;
  const int gx0 = blockIdx.x * BTX;   // first output col of block
  const int gy0 = blockIdx.y * BTY;   // first output row of block

  // ---- stage input tile (rows gy0..gy0+45, cols gx0..gx0+271) ----
  // 46 rows x 68 float4 per row = 3128 float4, 256 threads -> 13 iters
  for (int idx = tid; idx < TIN_Y * (TIN_XP / 4); idx += 256) {
    const int r  = idx / (TIN_XP / 4);
    const int c4 = (idx - r * (TIN_XP / 4)) * 4;
    const int gr = gy0 + r;
    const int gc = gx0 + c4;
    float4 v = make_float4(0.f, 0.f, 0.f, 0.f);
    if (gr < IN_DIM) {
      const float* row = X + (size_t)gr * IN_DIM;
      if (gc + 3 < IN_DIM) {
        v = *reinterpret_cast<const float4*>(row + gc);
      } else {
        if (gc + 0 < IN_DIM) v.x = row[gc + 0];
        if (gc + 1 < IN_DIM) v.y = row[gc + 1];
        if (gc + 2 < IN_DIM) v.z = row[gc + 2];
        if (gc + 3 < IN_DIM) v.w = row[gc + 3];
      }
    }
    *reinterpret_cast<float4*>(sX + r * TIN_XP + c4) = v;
  }
  __syncthreads();

  // ---- compute ----
  const int tx = tid & 63;       // 0..63, wave lanes contiguous in x
  const int ty = tid >> 6;       // 0..3  (wave id)
  const int lcol  = tx * 4;      // local col of first output (16B aligned)
  const int lrow0 = ty * 8;      // local row of first output

  float acc[8][4];
#pragma unroll
  for (int i = 0; i < 8; ++i)
#pragma unroll
    for (int j = 0; j < 4; ++j) acc[i][j] = 0.f;

#pragma unroll 1
  for (int c = 0; c < NCH; ++c) {
    // weights for ky in [3c, 3c+3) -- uniform loads (scalar cache)
    float w[KCH][KDIM];
#pragma unroll
    for (int kyl = 0; kyl < KCH; ++kyl)
#pragma unroll
      for (int kx = 0; kx < KDIM; ++kx)
        w[kyl][kx] = Wt[(c * KCH + kyl) * KDIM + kx];

    // input rows needed this chunk: lrow0 + 3c + ir, ir in [0, 8+KCH-1)
#pragma unroll
    for (int ir = 0; ir < 8 + KCH - 1; ++ir) {
      float buf[20];
      const float* p = sX + (lrow0 + c * KCH + ir) * TIN_XP + lcol;
#pragma unroll
      for (int k = 0; k < 5; ++k) {
        const float4 v = *reinterpret_cast<const float4*>(p + k * 4);
        buf[k * 4 + 0] = v.x; buf[k * 4 + 1] = v.y;
        buf[k * 4 + 2] = v.z; buf[k * 4 + 3] = v.w;
      }
#pragma unroll
      for (int dy = 0; dy < 8; ++dy) {
        const int kyl = ir - dy;            // compile-time after unroll
        if (kyl >= 0 && kyl < KCH) {
#pragma unroll
          for (int kx = 0; kx < KDIM; ++kx)
#pragma unroll
            for (int j = 0; j < 4; ++j)
              acc[dy][j] = fmaf(buf[kx + j], w[kyl][kx], acc[dy][j]);
        }
      }
    }
  }

  // ---- store (guarded, element-wise: 4082 % 4 != 0) ----
  const float b = bias[0];
#pragma unroll
  for (int dy = 0; dy < 8; ++dy) {
    const int oy = gy0 + lrow0 + dy;
    if (oy < OUT_DIM) {
      const int ox = gx0 + lcol;
      float* orow = out + (size_t)oy * OUT_DIM;
#pragma unroll
      for (int j = 0; j < 4; ++j)
        if (ox + j < OUT_DIM) orow[ox + j] = acc[dy][j] + b;
    }
  }
}

extern "C" void kernel_launch(void* const* d_in, const int* in_sizes, int n_in,
                              void* d_out, int out_size, void* d_ws, size_t ws_size,
                              hipStream_t stream) {
  const float* X    = (const float*)d_in[0];
  const float* Wt   = (const float*)d_in[1];
  const float* bias = (const float*)d_in[2];
  float* out = (float*)d_out;

  dim3 grid((OUT_DIM + BTX - 1) / BTX,    // 16
            (OUT_DIM + BTY - 1) / BTY);   // 128
  conv15_kernel<<<grid, 256, 0, stream>>>(X, Wt, bias, out);
}